// Round 1
// baseline (14745.305 us; speedup 1.0000x reference)
//
#include <hip/hip_runtime.h>
#include <math.h>

namespace {

constexpr int B_  = 2048;
constexpr int T_  = 100;
constexpr int D_  = 128;
constexpr int BT_ = B_ * T_;     // 204800
constexpr int R_  = 16;          // rows per block

enum { MODE_ENC = 0, MODE_ID = 1, MODE_TANH = 2 };

// One dense layer K->N computed from LDS activations into LDS output.
// 256 threads: ct = tid&15 owns 4 consecutive cols per 64-col tile,
// rt = tid>>4 owns one row. LDS strides padded +4 floats (bank-safe, 16B aligned).
template <int K, int N, bool RELU>
__device__ __forceinline__ void layer_lds(const float* __restrict__ a, float* __restrict__ o,
                                          const float* __restrict__ W, const float* __restrict__ bias,
                                          int tid) {
  const int ct = tid & 15;
  const int rt = tid >> 4;
  const float* arow = a + rt * (K + 4);
#pragma unroll
  for (int tile = 0; tile < N / 64; ++tile) {
    const int j = tile * 64 + ct * 4;
    float4 acc = *reinterpret_cast<const float4*>(bias + j);
    const float* wp = W + j;
#pragma unroll 8
    for (int k = 0; k < K; ++k) {
      const float av = arow[k];
      const float4 w = *reinterpret_cast<const float4*>(wp + (size_t)k * N);
      acc.x = fmaf(av, w.x, acc.x);
      acc.y = fmaf(av, w.y, acc.y);
      acc.z = fmaf(av, w.z, acc.z);
      acc.w = fmaf(av, w.w, acc.w);
    }
    if (RELU) {
      acc.x = fmaxf(acc.x, 0.0f);
      acc.y = fmaxf(acc.y, 0.0f);
      acc.z = fmaxf(acc.z, 0.0f);
      acc.w = fmaxf(acc.w, 0.0f);
    }
    *reinterpret_cast<float4*>(&o[rt * (N + 4) + j]) = acc;
  }
}

// Final layer K->128, stores straight to global rows given by sRow[].
template <int K>
__device__ __forceinline__ void layer_out(const float* __restrict__ a,
                                          const float* __restrict__ W, const float* __restrict__ bias,
                                          float* __restrict__ gout, const int* __restrict__ sRow,
                                          int tid) {
  constexpr int N = 128;
  const int ct = tid & 15;
  const int rt = tid >> 4;
  const float* arow = a + rt * (K + 4);
  float* gr = gout + (size_t)sRow[rt] * N;
#pragma unroll
  for (int tile = 0; tile < N / 64; ++tile) {
    const int j = tile * 64 + ct * 4;
    float4 acc = *reinterpret_cast<const float4*>(bias + j);
    const float* wp = W + j;
#pragma unroll 8
    for (int k = 0; k < K; ++k) {
      const float av = arow[k];
      const float4 w = *reinterpret_cast<const float4*>(wp + (size_t)k * N);
      acc.x = fmaf(av, w.x, acc.x);
      acc.y = fmaf(av, w.y, acc.y);
      acc.z = fmaf(av, w.z, acc.z);
      acc.w = fmaf(av, w.w, acc.w);
    }
    *reinterpret_cast<float4*>(gr + j) = acc;
  }
}

// Fused 3-layer MLP: in(128) -> N0 (relu) -> N1 (relu) -> 128.
// MODE_ENC : nan-clean input; side-write t==0 rows (cleaned x0) to xpred0.
// MODE_ID  : plain rows (recon decoder).
// MODE_TANH: row rl -> (b = rl/99, t = rl%99+1), read z[b,t,:], tanh on load,
//            output goes to the same (b,t) row of x_pred.
template <int N0, int N1, int MODE>
__launch_bounds__(256, 2)
__global__ void mlp3_kernel(const float* __restrict__ in,
                            const float* __restrict__ W0, const float* __restrict__ b0,
                            const float* __restrict__ W1, const float* __restrict__ b1,
                            const float* __restrict__ W2, const float* __restrict__ b2,
                            float* __restrict__ gout,
                            float* __restrict__ xpred0) {
  constexpr int K0 = 128;
  __shared__ float sIn[R_ * (K0 + 4)];
  __shared__ float sA[R_ * (N0 + 4)];
  __shared__ float sB[R_ * (N1 + 4)];
  __shared__ int sRow[R_];

  const int tid = threadIdx.x;
  const int r0 = blockIdx.x * R_;

  // ---- stage input: 16 rows x 128 floats = 512 float4, 2 per thread ----
#pragma unroll
  for (int i = 0; i < 2; ++i) {
    const int fi = tid + i * 256;
    const int r = fi >> 5;           // 32 float4 per row
    const int c = (fi & 31) << 2;    // float column
    const int rl = r0 + r;
    int g;
    if constexpr (MODE == MODE_TANH) {
      const int b = rl / 99;
      const int t = rl - b * 99 + 1;
      g = b * T_ + t;
    } else {
      g = rl;
    }
    if ((fi & 31) == 0) sRow[r] = g;
    float4 v = *reinterpret_cast<const float4*>(in + (size_t)g * K0 + c);
    if constexpr (MODE == MODE_ENC) {
      v.x = (v.x == v.x) ? v.x : 0.0f;
      v.y = (v.y == v.y) ? v.y : 0.0f;
      v.z = (v.z == v.z) ? v.z : 0.0f;
      v.w = (v.w == v.w) ? v.w : 0.0f;
      if (g % T_ == 0) {  // x_pred[:,0,:] = cleaned x[:,0,:]
        *reinterpret_cast<float4*>(xpred0 + (size_t)g * K0 + c) = v;
      }
    }
    if constexpr (MODE == MODE_TANH) {
      v.x = tanhf(v.x); v.y = tanhf(v.y); v.z = tanhf(v.z); v.w = tanhf(v.w);
    }
    *reinterpret_cast<float4*>(&sIn[r * (K0 + 4) + c]) = v;
  }
  __syncthreads();

  layer_lds<K0, N0, true>(sIn, sA, W0, b0, tid);
  __syncthreads();
  layer_lds<N0, N1, true>(sA, sB, W1, b1, tid);
  __syncthreads();
  layer_out<N1>(sB, W2, b2, gout, sRow, tid);
}

// RNN scan: one wave per batch row b. Lane l holds units (l, l+64) of h.
// h_{t+1} = h + 0.2*(-h + tanh(h) @ n @ m.T / 128) + 0.05*noise[:,t,:]
// z[b,0,:] (== h0 == h_enc[b,0,:]) is already in place; we write t=1..99.
__global__ void rnn_scan_kernel(const float* __restrict__ noise,
                                const float* __restrict__ m, const float* __restrict__ n,
                                float* __restrict__ z) {
  const int gtid = blockIdx.x * blockDim.x + threadIdx.x;
  const int b = gtid >> 6;
  const int lane = threadIdx.x & 63;
  const int k0 = lane, k1 = lane + 64;

  const float mk00 = m[k0 * 2], mk01 = m[k0 * 2 + 1];
  const float mk10 = m[k1 * 2], mk11 = m[k1 * 2 + 1];
  const float nk00 = n[k0 * 2], nk01 = n[k0 * 2 + 1];
  const float nk10 = n[k1 * 2], nk11 = n[k1 * 2 + 1];

  float* zb = z + (size_t)b * T_ * D_;
  const float* nzb = noise + (size_t)b * (T_ - 1) * D_;
  float h0 = zb[k0];
  float h1 = zb[k1];

#pragma unroll 1
  for (int t = 0; t < T_ - 1; ++t) {
    const float r0v = tanhf(h0);
    const float r1v = tanhf(h1);
    float p0 = r0v * nk00 + r1v * nk10;   // partial of tanh(h) @ n column 0
    float p1 = r0v * nk01 + r1v * nk11;   // column 1
#pragma unroll
    for (int off = 32; off > 0; off >>= 1) {
      p0 += __shfl_xor(p0, off);
      p1 += __shfl_xor(p1, off);
    }
    const float v0 = (p0 * mk00 + p1 * mk01) * (1.0f / 128.0f);
    const float v1 = (p0 * mk10 + p1 * mk11) * (1.0f / 128.0f);
    const float nz0 = nzb[t * D_ + k0];
    const float nz1 = nzb[t * D_ + k1];
    h0 += 0.2f * (v0 - h0) + 0.05f * nz0;
    h1 += 0.2f * (v1 - h1) + 0.05f * nz1;
    zb[(t + 1) * D_ + k0] = h0;
    zb[(t + 1) * D_ + k1] = h1;
  }
}

}  // namespace

extern "C" void kernel_launch(void* const* d_in, const int* in_sizes, int n_in,
                              void* d_out, int out_size, void* d_ws, size_t ws_size,
                              hipStream_t stream) {
  (void)in_sizes; (void)n_in; (void)d_ws; (void)ws_size; (void)out_size;

  const float* x     = (const float*)d_in[0];
  const float* noise = (const float*)d_in[1];
  // d_in[2] = seq_len (==100), folded into compile-time constants
  const float* e_w0 = (const float*)d_in[3];
  const float* e_b0 = (const float*)d_in[4];
  const float* e_w1 = (const float*)d_in[5];
  const float* e_b1 = (const float*)d_in[6];
  const float* e_w2 = (const float*)d_in[7];
  const float* e_b2 = (const float*)d_in[8];
  const float* d_w0 = (const float*)d_in[9];
  const float* d_b0 = (const float*)d_in[10];
  const float* d_w1 = (const float*)d_in[11];
  const float* d_b1 = (const float*)d_in[12];
  const float* d_w2 = (const float*)d_in[13];
  const float* d_b2 = (const float*)d_in[14];
  const float* m    = (const float*)d_in[15];
  const float* n    = (const float*)d_in[16];

  float* out    = (float*)d_out;
  float* x_pred = out;                          // (B,T,128)
  float* x_rec  = out + (size_t)BT_ * D_;       // (B,T,128)
  float* z      = out + 2 * (size_t)BT_ * D_;   // (B,T,128): h_enc, then h-sequence

  // 1) encoder: x -> h_enc (stored in z region); also x_pred[:,0,:] = clean(x[:,0,:])
  mlp3_kernel<512, 256, MODE_ENC><<<BT_ / R_, 256, 0, stream>>>(
      x, e_w0, e_b0, e_w1, e_b1, e_w2, e_b2, z, x_pred);

  // 2) recon decoder: h_enc -> x_reconstruct
  mlp3_kernel<256, 512, MODE_ID><<<BT_ / R_, 256, 0, stream>>>(
      z, d_w0, d_b0, d_w1, d_b1, d_w2, d_b2, x_rec, nullptr);

  // 3) RNN scan: overwrite z[:,1:,:] with h_1..h_99 (z[:,0,:] already == h0)
  rnn_scan_kernel<<<B_ / 4, 256, 0, stream>>>(noise, m, n, z);

  // 4) pred decoder: decoder(tanh(z[:,1:,:])) -> x_pred[:,1:,:]
  mlp3_kernel<256, 512, MODE_TANH><<<(B_ * (T_ - 1)) / R_, 256, 0, stream>>>(
      z, d_w0, d_b0, d_w1, d_b1, d_w2, d_b2, x_pred, nullptr);
}

// Round 2
// 1073.173 us; speedup vs baseline: 13.7399x; 13.7399x over previous
//
#include <hip/hip_runtime.h>
#include <math.h>

namespace {

constexpr int B_  = 2048;
constexpr int T_  = 100;
constexpr int D_  = 128;
constexpr int BT_ = B_ * T_;     // 204800
constexpr int MT_ = 32;          // rows per block (M-tile)

using f32x4  = __attribute__((ext_vector_type(4))) float;
using bf16x8 = __attribute__((ext_vector_type(8))) __bf16;

enum { MODE_ENC = 0, MODE_ID = 1, MODE_TANH = 2 };

__device__ __forceinline__ unsigned short f2bf(float f) {
  unsigned int u = __float_as_uint(f);           // RNE round to bf16
  return (unsigned short)((u + 0x7FFFu + ((u >> 16) & 1u)) >> 16);
}
__device__ __forceinline__ unsigned int pack2(float a, float b) {
  return (unsigned int)f2bf(a) | ((unsigned int)f2bf(b) << 16);
}

// ---- one dense layer via MFMA -------------------------------------------
// A: 32 rows of bf16 activations in LDS `src`, row stride K*2 bytes,
//    XOR-swizzled: byte_off ^= (row&7)<<4.
// B: global bf16 weights Wt[NTOT][K] (k-contiguous per output col).
// Wave `wave` computes output cols [wave*NTOT/4, (wave+1)*NTOT/4).
// FINAL=false: +bias, relu, bf16 -> LDS dst (row stride NTOT*2, swizzled).
// FINAL=true : +bias -> global f32 rows sRow[].
template <int K, int NTOT, bool FINAL>
__device__ __forceinline__ void layer(const char* __restrict__ src, char* __restrict__ dst,
                                      const unsigned short* __restrict__ Wt,
                                      const float* __restrict__ bias,
                                      float* __restrict__ gout, const int* __restrict__ sRow,
                                      int wave, int lane) {
  constexpr int NT = NTOT / 64;        // 16-col tiles per wave
  const int lrow = lane & 15;
  const int lk   = lane >> 4;
  const int n0w  = wave * (NTOT / 4);
  const int akey = (lrow & 7) << 4;    // same key for row and row+16

#pragma unroll
  for (int nt = 0; nt < NT; ++nt) {
    const int col = n0w + nt * 16 + lrow;
    f32x4 acc0 = {0.f, 0.f, 0.f, 0.f};
    f32x4 acc1 = {0.f, 0.f, 0.f, 0.f};
    const unsigned short* wp = Wt + (size_t)col * K + lk * 8;
#pragma unroll
    for (int kk = 0; kk < K / 32; ++kk) {
      const int off = kk * 64 + lk * 16;
      const int4 ra0 = *reinterpret_cast<const int4*>(src + lrow * (K * 2) + (off ^ akey));
      const int4 ra1 = *reinterpret_cast<const int4*>(src + (lrow + 16) * (K * 2) + (off ^ akey));
      const int4 rb  = *reinterpret_cast<const int4*>(wp + kk * 32);
      const bf16x8 a0 = __builtin_bit_cast(bf16x8, ra0);
      const bf16x8 a1 = __builtin_bit_cast(bf16x8, ra1);
      const bf16x8 b  = __builtin_bit_cast(bf16x8, rb);
      acc0 = __builtin_amdgcn_mfma_f32_16x16x32_bf16(a0, b, acc0, 0, 0, 0);
      acc1 = __builtin_amdgcn_mfma_f32_16x16x32_bf16(a1, b, acc1, 0, 0, 0);
    }
    const float bv = bias[col];
    if constexpr (FINAL) {
#pragma unroll
      for (int j = 0; j < 4; ++j) {
        const int r0 = lk * 4 + j;
        gout[(size_t)sRow[r0] * 128 + col]      = acc0[j] + bv;
        gout[(size_t)sRow[r0 + 16] * 128 + col] = acc1[j] + bv;
      }
    } else {
#pragma unroll
      for (int j = 0; j < 4; ++j) {
        const int r0 = lk * 4 + j;
        const int r1 = r0 + 16;
        const float v0 = fmaxf(acc0[j] + bv, 0.f);
        const float v1 = fmaxf(acc1[j] + bv, 0.f);
        *reinterpret_cast<unsigned short*>(dst + r0 * (NTOT * 2) + ((col * 2) ^ ((r0 & 7) << 4))) = f2bf(v0);
        *reinterpret_cast<unsigned short*>(dst + r1 * (NTOT * 2) + ((col * 2) ^ ((r1 & 7) << 4))) = f2bf(v1);
      }
    }
  }
}

// ---- fused 3-layer MLP: 128 -> N0 (relu) -> N1 (relu) -> 128 ------------
template <int N0, int N1, int MODE>
__launch_bounds__(256, 3)
__global__ void mlp3_kernel(const float* __restrict__ in,
                            const unsigned short* __restrict__ Wt0, const float* __restrict__ b0,
                            const unsigned short* __restrict__ Wt1, const float* __restrict__ b1,
                            const unsigned short* __restrict__ Wt2, const float* __restrict__ b2,
                            float* __restrict__ gout,
                            float* __restrict__ xpred0) {
  constexpr int XB = (MT_ * N1 * 2 > MT_ * 128 * 2) ? MT_ * N1 * 2 : MT_ * 128 * 2;
  constexpr int YB = MT_ * N0 * 2;
  __shared__ __align__(16) char X[XB];   // sIn, later sMid1
  __shared__ __align__(16) char Y[YB];   // sMid0
  __shared__ int sRow[MT_];

  const int tid  = threadIdx.x;
  const int wave = tid >> 6;
  const int lane = tid & 63;
  const int r0   = blockIdx.x * MT_;

  // stage: 32 rows x 128 f32 -> bf16 LDS, 16B chunk per thread x2
#pragma unroll
  for (int i = 0; i < 2; ++i) {
    const int c   = tid + i * 256;
    const int row = c >> 4;        // 16 chunks (of 8 floats) per row
    const int cb  = c & 15;
    const int rl  = r0 + row;
    int g;
    if constexpr (MODE == MODE_TANH) {
      const int b = rl / 99;
      g = b * T_ + (rl - b * 99) + 1;
    } else {
      g = rl;
    }
    if (cb == 0) sRow[row] = g;
    const float4* gp = reinterpret_cast<const float4*>(in + (size_t)g * 128 + cb * 8);
    float4 v0 = gp[0], v1 = gp[1];
    if constexpr (MODE == MODE_ENC) {
      v0.x = (v0.x == v0.x) ? v0.x : 0.f;  v0.y = (v0.y == v0.y) ? v0.y : 0.f;
      v0.z = (v0.z == v0.z) ? v0.z : 0.f;  v0.w = (v0.w == v0.w) ? v0.w : 0.f;
      v1.x = (v1.x == v1.x) ? v1.x : 0.f;  v1.y = (v1.y == v1.y) ? v1.y : 0.f;
      v1.z = (v1.z == v1.z) ? v1.z : 0.f;  v1.w = (v1.w == v1.w) ? v1.w : 0.f;
      if (rl % T_ == 0) {   // x_pred[:,0,:] = cleaned x[:,0,:]
        float4* xp = reinterpret_cast<float4*>(xpred0 + (size_t)g * 128 + cb * 8);
        xp[0] = v0; xp[1] = v1;
      }
    }
    if constexpr (MODE == MODE_TANH) {
      v0.x = tanhf(v0.x); v0.y = tanhf(v0.y); v0.z = tanhf(v0.z); v0.w = tanhf(v0.w);
      v1.x = tanhf(v1.x); v1.y = tanhf(v1.y); v1.z = tanhf(v1.z); v1.w = tanhf(v1.w);
    }
    int4 pk;
    pk.x = (int)pack2(v0.x, v0.y); pk.y = (int)pack2(v0.z, v0.w);
    pk.z = (int)pack2(v1.x, v1.y); pk.w = (int)pack2(v1.z, v1.w);
    *reinterpret_cast<int4*>(X + row * 256 + ((cb * 16) ^ ((row & 7) << 4))) = pk;
  }
  __syncthreads();

  layer<128, N0, false>(X, Y, Wt0, b0, nullptr, nullptr, wave, lane);
  __syncthreads();
  layer<N0, N1, false>(Y, X, Wt1, b1, nullptr, nullptr, wave, lane);
  __syncthreads();
  layer<N1, 128, true>(X, nullptr, Wt2, b2, gout, sRow, wave, lane);
}

// ---- weight prep: fp32 [K][N] -> bf16 [N][K] ----------------------------
__global__ void wprep_kernel(const float* __restrict__ src, unsigned short* __restrict__ dst,
                             int K, int N) {
  const int id = blockIdx.x * blockDim.x + threadIdx.x;
  if (id >= K * N) return;
  const int k = id / N;
  const int n = id - k * N;
  dst[(size_t)n * K + k] = f2bf(src[id]);
}

// ---- RNN scan (fp32, sequential, tiny) ----------------------------------
__global__ void rnn_scan_kernel(const float* __restrict__ noise,
                                const float* __restrict__ m, const float* __restrict__ n,
                                float* __restrict__ z) {
  const int gtid = blockIdx.x * blockDim.x + threadIdx.x;
  const int b = gtid >> 6;
  const int lane = threadIdx.x & 63;
  const int k0 = lane, k1 = lane + 64;

  const float mk00 = m[k0 * 2], mk01 = m[k0 * 2 + 1];
  const float mk10 = m[k1 * 2], mk11 = m[k1 * 2 + 1];
  const float nk00 = n[k0 * 2], nk01 = n[k0 * 2 + 1];
  const float nk10 = n[k1 * 2], nk11 = n[k1 * 2 + 1];

  float* zb = z + (size_t)b * T_ * D_;
  const float* nzb = noise + (size_t)b * (T_ - 1) * D_;
  float h0 = zb[k0];
  float h1 = zb[k1];

#pragma unroll 1
  for (int t = 0; t < T_ - 1; ++t) {
    const float r0v = tanhf(h0);
    const float r1v = tanhf(h1);
    float p0 = r0v * nk00 + r1v * nk10;
    float p1 = r0v * nk01 + r1v * nk11;
#pragma unroll
    for (int off = 32; off > 0; off >>= 1) {
      p0 += __shfl_xor(p0, off);
      p1 += __shfl_xor(p1, off);
    }
    const float v0 = (p0 * mk00 + p1 * mk01) * (1.0f / 128.0f);
    const float v1 = (p0 * mk10 + p1 * mk11) * (1.0f / 128.0f);
    const float nz0 = nzb[t * D_ + k0];
    const float nz1 = nzb[t * D_ + k1];
    h0 += 0.2f * (v0 - h0) + 0.05f * nz0;
    h1 += 0.2f * (v1 - h1) + 0.05f * nz1;
    zb[(t + 1) * D_ + k0] = h0;
    zb[(t + 1) * D_ + k1] = h1;
  }
}

}  // namespace

extern "C" void kernel_launch(void* const* d_in, const int* in_sizes, int n_in,
                              void* d_out, int out_size, void* d_ws, size_t ws_size,
                              hipStream_t stream) {
  (void)in_sizes; (void)n_in; (void)ws_size; (void)out_size;

  const float* x     = (const float*)d_in[0];
  const float* noise = (const float*)d_in[1];
  const float* e_w0 = (const float*)d_in[3];
  const float* e_b0 = (const float*)d_in[4];
  const float* e_w1 = (const float*)d_in[5];
  const float* e_b1 = (const float*)d_in[6];
  const float* e_w2 = (const float*)d_in[7];
  const float* e_b2 = (const float*)d_in[8];
  const float* d_w0 = (const float*)d_in[9];
  const float* d_b0 = (const float*)d_in[10];
  const float* d_w1 = (const float*)d_in[11];
  const float* d_b1 = (const float*)d_in[12];
  const float* d_w2 = (const float*)d_in[13];
  const float* d_b2 = (const float*)d_in[14];
  const float* m    = (const float*)d_in[15];
  const float* n    = (const float*)d_in[16];

  float* out    = (float*)d_out;
  float* x_pred = out;                          // (B,T,128)
  float* x_rec  = out + (size_t)BT_ * D_;       // (B,T,128)
  float* z      = out + 2 * (size_t)BT_ * D_;   // (B,T,128)

  // bf16 transposed weights in d_ws
  unsigned short* ws = (unsigned short*)d_ws;
  unsigned short* eW0t = ws;            // 512x128
  unsigned short* eW1t = ws + 65536;    // 256x512
  unsigned short* eW2t = ws + 196608;   // 128x256
  unsigned short* dW0t = ws + 229376;   // 256x128
  unsigned short* dW1t = ws + 262144;   // 512x256
  unsigned short* dW2t = ws + 393216;   // 128x512

  wprep_kernel<<<(65536 + 255) / 256, 256, 0, stream>>>(e_w0, eW0t, 128, 512);
  wprep_kernel<<<(131072 + 255) / 256, 256, 0, stream>>>(e_w1, eW1t, 512, 256);
  wprep_kernel<<<(32768 + 255) / 256, 256, 0, stream>>>(e_w2, eW2t, 256, 128);
  wprep_kernel<<<(32768 + 255) / 256, 256, 0, stream>>>(d_w0, dW0t, 128, 256);
  wprep_kernel<<<(131072 + 255) / 256, 256, 0, stream>>>(d_w1, dW1t, 256, 512);
  wprep_kernel<<<(65536 + 255) / 256, 256, 0, stream>>>(d_w2, dW2t, 512, 128);

  // 1) encoder: x -> h_enc (z region); side-writes x_pred[:,0,:]
  mlp3_kernel<512, 256, MODE_ENC><<<BT_ / MT_, 256, 0, stream>>>(
      x, eW0t, e_b0, eW1t, e_b1, eW2t, e_b2, z, x_pred);

  // 2) recon decoder: h_enc -> x_reconstruct
  mlp3_kernel<256, 512, MODE_ID><<<BT_ / MT_, 256, 0, stream>>>(
      z, dW0t, d_b0, dW1t, d_b1, dW2t, d_b2, x_rec, nullptr);

  // 3) RNN scan: z[:,1:,:] = h_1..h_99 (z[:,0,:] already h0)
  rnn_scan_kernel<<<B_ / 4, 256, 0, stream>>>(noise, m, n, z);

  // 4) pred decoder: decoder(tanh(z[:,1:,:])) -> x_pred[:,1:,:]
  mlp3_kernel<256, 512, MODE_TANH><<<(B_ * (T_ - 1)) / MT_, 256, 0, stream>>>(
      z, dW0t, d_b0, dW1t, d_b1, dW2t, d_b2, x_pred, nullptr);
}

// Round 3
// 795.152 us; speedup vs baseline: 18.5440x; 1.3496x over previous
//
#include <hip/hip_runtime.h>
#include <math.h>

namespace {

constexpr int B_  = 2048;
constexpr int T_  = 100;
constexpr int D_  = 128;
constexpr int BT_ = B_ * T_;     // 204800
constexpr int M_  = 64;          // rows per block

using f32x4  = __attribute__((ext_vector_type(4))) float;
using bf16x8 = __attribute__((ext_vector_type(8))) __bf16;

enum { MODE_ENC = 0, MODE_ID = 1, MODE_TANH = 2 };

__device__ __forceinline__ unsigned short f2bf(float f) {
  unsigned int u = __float_as_uint(f);           // RNE round to bf16
  return (unsigned short)((u + 0x7FFFu + ((u >> 16) & 1u)) >> 16);
}
__device__ __forceinline__ unsigned int pack2(float a, float b) {
  return (unsigned int)f2bf(a) | ((unsigned int)f2bf(b) << 16);
}
__device__ __forceinline__ float ftanh(float x) {   // feeds bf16; err ~1e-6 << bf16 ulp
  const float e = __expf(2.0f * x);
  return 1.0f - 2.0f / (e + 1.0f);
}

// ---- MFMA GEMM accumulate ------------------------------------------------
// src: 64 rows bf16 in LDS, row stride strideB bytes, 16B slots XOR-swizzled
// by ((row&15)<<4). Wt: bf16 [cols][KFULL], pre-offset to this wave's col0
// and k0. acc[nt][s]: col-tile nt (16 cols), row-subtile s (rows s*16..+16).
template <int K, int NT, int KFULL>
__device__ __forceinline__ void gemm_acc(const char* __restrict__ src, const int strideB,
                                         const unsigned short* __restrict__ Wt,
                                         f32x4 (&acc)[NT][4], const int lrow, const int lk) {
  const int key = lrow << 4;
#pragma unroll
  for (int kk = 0; kk < K / 32; ++kk) {
    bf16x8 a[4];
#pragma unroll
    for (int s = 0; s < 4; ++s) {
      const int row = lrow + s * 16;
      a[s] = __builtin_bit_cast(bf16x8,
          *reinterpret_cast<const int4*>(src + row * strideB + ((kk * 64 + lk * 16) ^ key)));
    }
#pragma unroll
    for (int nt = 0; nt < NT; ++nt) {
      const bf16x8 b = __builtin_bit_cast(bf16x8,
          *reinterpret_cast<const int4*>(Wt + (size_t)(nt * 16 + lrow) * KFULL + kk * 32 + lk * 8));
#pragma unroll
      for (int s = 0; s < 4; ++s)
        acc[nt][s] = __builtin_amdgcn_mfma_f32_16x16x32_bf16(a[s], b, acc[nt][s], 0, 0, 0);
    }
  }
}

template <int NT>
__device__ __forceinline__ void init_bias(f32x4 (&acc)[NT][4], const float* __restrict__ bias,
                                          const int col0, const int lrow) {
#pragma unroll
  for (int nt = 0; nt < NT; ++nt) {
    const float bv = bias[col0 + nt * 16 + lrow];
#pragma unroll
    for (int s = 0; s < 4; ++s) acc[nt][s] = {bv, bv, bv, bv};
  }
}

// relu + bf16 store of acc to LDS (row stride strideB, swizzled).
template <int NT>
__device__ __forceinline__ void store_lds(char* __restrict__ dst, const int strideB,
                                          const int colLocal0, f32x4 (&acc)[NT][4],
                                          const int lrow, const int lk) {
#pragma unroll
  for (int nt = 0; nt < NT; ++nt) {
    const int col = colLocal0 + nt * 16 + lrow;
#pragma unroll
    for (int s = 0; s < 4; ++s)
#pragma unroll
      for (int j = 0; j < 4; ++j) {
        const int row = s * 16 + lk * 4 + j;
        *reinterpret_cast<unsigned short*>(dst + row * strideB + ((col * 2) ^ ((row & 15) << 4))) =
            f2bf(fmaxf(acc[nt][s][j], 0.0f));
      }
  }
}

// stage 64 rows x 128 f32 -> bf16 LDS X (stride 256B, swizzled); 512 threads.
template <int MODE>
__device__ __forceinline__ void stage(const float* __restrict__ in, char* __restrict__ X,
                                      int* __restrict__ sRow, float* __restrict__ xpred0,
                                      const int r0, const int tid) {
#pragma unroll
  for (int i = 0; i < 2; ++i) {
    const int c   = tid + i * 512;   // 1024 chunks of 8 floats
    const int row = c >> 4;
    const int cb  = c & 15;
    const int rl  = r0 + row;
    int g;
    if constexpr (MODE == MODE_TANH) {
      const int b = rl / 99;
      g = b * T_ + (rl - b * 99) + 1;
    } else {
      g = rl;
    }
    if (cb == 0) sRow[row] = g;
    const float4* gp = reinterpret_cast<const float4*>(in + (size_t)g * 128 + cb * 8);
    float4 v0 = gp[0], v1 = gp[1];
    if constexpr (MODE == MODE_ENC) {
      v0.x = (v0.x == v0.x) ? v0.x : 0.f;  v0.y = (v0.y == v0.y) ? v0.y : 0.f;
      v0.z = (v0.z == v0.z) ? v0.z : 0.f;  v0.w = (v0.w == v0.w) ? v0.w : 0.f;
      v1.x = (v1.x == v1.x) ? v1.x : 0.f;  v1.y = (v1.y == v1.y) ? v1.y : 0.f;
      v1.z = (v1.z == v1.z) ? v1.z : 0.f;  v1.w = (v1.w == v1.w) ? v1.w : 0.f;
      if (rl % T_ == 0) {   // x_pred[:,0,:] = cleaned x[:,0,:]
        float4* xp = reinterpret_cast<float4*>(xpred0 + (size_t)g * 128 + cb * 8);
        xp[0] = v0; xp[1] = v1;
      }
    }
    if constexpr (MODE == MODE_TANH) {
      v0.x = ftanh(v0.x); v0.y = ftanh(v0.y); v0.z = ftanh(v0.z); v0.w = ftanh(v0.w);
      v1.x = ftanh(v1.x); v1.y = ftanh(v1.y); v1.z = ftanh(v1.z); v1.w = ftanh(v1.w);
    }
    int4 pk;
    pk.x = (int)pack2(v0.x, v0.y); pk.y = (int)pack2(v0.z, v0.w);
    pk.z = (int)pack2(v1.x, v1.y); pk.w = (int)pack2(v1.z, v1.w);
    *reinterpret_cast<int4*>(X + row * 256 + ((cb * 16) ^ ((row & 15) << 4))) = pk;
  }
}

// final-layer epilogue: acc (NT=1, 16 cols) + rows sRow -> global f32
__device__ __forceinline__ void store_global(float* __restrict__ gout, const int* __restrict__ sRow,
                                             f32x4 (&acc)[1][4], const int wave,
                                             const int lrow, const int lk) {
  const int col = wave * 16 + lrow;
#pragma unroll
  for (int s = 0; s < 4; ++s)
#pragma unroll
    for (int j = 0; j < 4; ++j) {
      const int row = s * 16 + lk * 4 + j;
      gout[(size_t)sRow[row] * 128 + col] = acc[0][s][j];
    }
}

// ---- encoder: 128 -> 512(relu) -> 256(relu) -> 128 ----------------------
// a1 computed in 256-col halves (Y=32KB); a2 accumulated in registers.
__launch_bounds__(512, 4)
__global__ void enc_kernel(const float* __restrict__ in,
                           const unsigned short* __restrict__ W0t, const float* __restrict__ b0,
                           const unsigned short* __restrict__ W1t, const float* __restrict__ b1,
                           const unsigned short* __restrict__ W2t, const float* __restrict__ b2,
                           float* __restrict__ gout, float* __restrict__ xpred0) {
  __shared__ __align__(16) char X[M_ * 512];
  __shared__ __align__(16) char Y[M_ * 512];
  __shared__ int sRow[M_];

  const int tid  = threadIdx.x;
  const int wave = tid >> 6;
  const int lane = tid & 63;
  const int lrow = lane & 15;
  const int lk   = lane >> 4;
  const int r0   = blockIdx.x * M_;

  stage<MODE_ENC>(in, X, sRow, xpred0, r0, tid);
  __syncthreads();

  f32x4 acc2[2][4];
  init_bias<2>(acc2, b1, wave * 32, lrow);
#pragma unroll
  for (int h = 0; h < 2; ++h) {
    f32x4 acc1[2][4];
    init_bias<2>(acc1, b0, h * 256 + wave * 32, lrow);
    gemm_acc<128, 2, 128>(X, 256, W0t + (size_t)(h * 256 + wave * 32) * 128, acc1, lrow, lk);
    __syncthreads();                       // prev-half L2 readers of Y done
    store_lds<2>(Y, 512, wave * 32, acc1, lrow, lk);
    __syncthreads();
    gemm_acc<256, 2, 512>(Y, 512, W1t + (size_t)(wave * 32) * 512 + h * 256, acc2, lrow, lk);
  }
  store_lds<2>(X, 512, wave * 32, acc2, lrow, lk);   // all L1 X-reads done (loop barrier)
  __syncthreads();

  f32x4 acc3[1][4];
  init_bias<1>(acc3, b2, wave * 16, lrow);
  gemm_acc<256, 1, 256>(X, 512, W2t + (size_t)(wave * 16) * 256, acc3, lrow, lk);
  store_global(gout, sRow, acc3, wave, lrow, lk);
}

// ---- decoder: 128 -> 256(relu) -> 512(relu) -> 128 ----------------------
// a2 computed in 256-col halves into X; final layer K-split accumulates.
template <int MODE>
__launch_bounds__(512, 4)
__global__ void dec_kernel(const float* __restrict__ in,
                           const unsigned short* __restrict__ W0t, const float* __restrict__ b0,
                           const unsigned short* __restrict__ W1t, const float* __restrict__ b1,
                           const unsigned short* __restrict__ W2t, const float* __restrict__ b2,
                           float* __restrict__ gout) {
  __shared__ __align__(16) char X[M_ * 512];
  __shared__ __align__(16) char Y[M_ * 512];
  __shared__ int sRow[M_];

  const int tid  = threadIdx.x;
  const int wave = tid >> 6;
  const int lane = tid & 63;
  const int lrow = lane & 15;
  const int lk   = lane >> 4;
  const int r0   = blockIdx.x * M_;

  stage<MODE>(in, X, sRow, nullptr, r0, tid);
  __syncthreads();

  f32x4 acc1[2][4];
  init_bias<2>(acc1, b0, wave * 32, lrow);
  gemm_acc<128, 2, 128>(X, 256, W0t + (size_t)(wave * 32) * 128, acc1, lrow, lk);
  store_lds<2>(Y, 512, wave * 32, acc1, lrow, lk);
  __syncthreads();

  f32x4 acc3[1][4];
  init_bias<1>(acc3, b2, wave * 16, lrow);
#pragma unroll
  for (int h = 0; h < 2; ++h) {
    f32x4 acc2[2][4];
    init_bias<2>(acc2, b1, h * 256 + wave * 32, lrow);
    gemm_acc<256, 2, 256>(Y, 512, W1t + (size_t)(h * 256 + wave * 32) * 256, acc2, lrow, lk);
    __syncthreads();                       // prior L3 X-reads (and L1 stage-X) done
    store_lds<2>(X, 512, wave * 32, acc2, lrow, lk);
    __syncthreads();
    gemm_acc<256, 1, 512>(X, 512, W2t + (size_t)(wave * 16) * 512 + h * 256, acc3, lrow, lk);
  }
  store_global(gout, sRow, acc3, wave, lrow, lk);
}

// ---- weight prep: fp32 [K][N] -> bf16 [N][K] ----------------------------
__global__ void wprep_kernel(const float* __restrict__ src, unsigned short* __restrict__ dst,
                             int K, int N) {
  const int id = blockIdx.x * blockDim.x + threadIdx.x;
  if (id >= K * N) return;
  const int k = id / N;
  const int n = id - k * N;
  dst[(size_t)n * K + k] = f2bf(src[id]);
}

// ---- RNN scan (fp32, sequential, tiny) ----------------------------------
__global__ void rnn_scan_kernel(const float* __restrict__ noise,
                                const float* __restrict__ m, const float* __restrict__ n,
                                float* __restrict__ z) {
  const int gtid = blockIdx.x * blockDim.x + threadIdx.x;
  const int b = gtid >> 6;
  const int lane = threadIdx.x & 63;
  const int k0 = lane, k1 = lane + 64;

  const float mk00 = m[k0 * 2], mk01 = m[k0 * 2 + 1];
  const float mk10 = m[k1 * 2], mk11 = m[k1 * 2 + 1];
  const float nk00 = n[k0 * 2], nk01 = n[k0 * 2 + 1];
  const float nk10 = n[k1 * 2], nk11 = n[k1 * 2 + 1];

  float* zb = z + (size_t)b * T_ * D_;
  const float* nzb = noise + (size_t)b * (T_ - 1) * D_;
  float h0 = zb[k0];
  float h1 = zb[k1];

#pragma unroll 1
  for (int t = 0; t < T_ - 1; ++t) {
    const float r0v = tanhf(h0);
    const float r1v = tanhf(h1);
    float p0 = r0v * nk00 + r1v * nk10;
    float p1 = r0v * nk01 + r1v * nk11;
#pragma unroll
    for (int off = 32; off > 0; off >>= 1) {
      p0 += __shfl_xor(p0, off);
      p1 += __shfl_xor(p1, off);
    }
    const float v0 = (p0 * mk00 + p1 * mk01) * (1.0f / 128.0f);
    const float v1 = (p0 * mk10 + p1 * mk11) * (1.0f / 128.0f);
    const float nz0 = nzb[t * D_ + k0];
    const float nz1 = nzb[t * D_ + k1];
    h0 += 0.2f * (v0 - h0) + 0.05f * nz0;
    h1 += 0.2f * (v1 - h1) + 0.05f * nz1;
    zb[(t + 1) * D_ + k0] = h0;
    zb[(t + 1) * D_ + k1] = h1;
  }
}

}  // namespace

extern "C" void kernel_launch(void* const* d_in, const int* in_sizes, int n_in,
                              void* d_out, int out_size, void* d_ws, size_t ws_size,
                              hipStream_t stream) {
  (void)in_sizes; (void)n_in; (void)ws_size; (void)out_size;

  const float* x     = (const float*)d_in[0];
  const float* noise = (const float*)d_in[1];
  const float* e_w0 = (const float*)d_in[3];
  const float* e_b0 = (const float*)d_in[4];
  const float* e_w1 = (const float*)d_in[5];
  const float* e_b1 = (const float*)d_in[6];
  const float* e_w2 = (const float*)d_in[7];
  const float* e_b2 = (const float*)d_in[8];
  const float* d_w0 = (const float*)d_in[9];
  const float* d_b0 = (const float*)d_in[10];
  const float* d_w1 = (const float*)d_in[11];
  const float* d_b1 = (const float*)d_in[12];
  const float* d_w2 = (const float*)d_in[13];
  const float* d_b2 = (const float*)d_in[14];
  const float* m    = (const float*)d_in[15];
  const float* n    = (const float*)d_in[16];

  float* out    = (float*)d_out;
  float* x_pred = out;                          // (B,T,128)
  float* x_rec  = out + (size_t)BT_ * D_;       // (B,T,128)
  float* z      = out + 2 * (size_t)BT_ * D_;   // (B,T,128)

  unsigned short* ws = (unsigned short*)d_ws;
  unsigned short* eW0t = ws;            // 512x128
  unsigned short* eW1t = ws + 65536;    // 256x512
  unsigned short* eW2t = ws + 196608;   // 128x256
  unsigned short* dW0t = ws + 229376;   // 256x128
  unsigned short* dW1t = ws + 262144;   // 512x256
  unsigned short* dW2t = ws + 393216;   // 128x512

  wprep_kernel<<<(65536 + 255) / 256, 256, 0, stream>>>(e_w0, eW0t, 128, 512);
  wprep_kernel<<<(131072 + 255) / 256, 256, 0, stream>>>(e_w1, eW1t, 512, 256);
  wprep_kernel<<<(32768 + 255) / 256, 256, 0, stream>>>(e_w2, eW2t, 256, 128);
  wprep_kernel<<<(32768 + 255) / 256, 256, 0, stream>>>(d_w0, dW0t, 128, 256);
  wprep_kernel<<<(131072 + 255) / 256, 256, 0, stream>>>(d_w1, dW1t, 256, 512);
  wprep_kernel<<<(65536 + 255) / 256, 256, 0, stream>>>(d_w2, dW2t, 512, 128);

  // 1) encoder: x -> h_enc (z region); side-writes x_pred[:,0,:]
  enc_kernel<<<BT_ / M_, 512, 0, stream>>>(x, eW0t, e_b0, eW1t, e_b1, eW2t, e_b2, z, x_pred);

  // 2) recon decoder: h_enc -> x_reconstruct
  dec_kernel<MODE_ID><<<BT_ / M_, 512, 0, stream>>>(z, dW0t, d_b0, dW1t, d_b1, dW2t, d_b2, x_rec);

  // 3) RNN scan: z[:,1:,:] = h_1..h_99 (z[:,0,:] already h0)
  rnn_scan_kernel<<<B_ / 4, 256, 0, stream>>>(noise, m, n, z);

  // 4) pred decoder: decoder(tanh(z[:,1:,:])) -> x_pred[:,1:,:]
  dec_kernel<MODE_TANH><<<(B_ * (T_ - 1)) / M_, 512, 0, stream>>>(z, dW0t, d_b0, dW1t, d_b1, dW2t, d_b2, x_pred);
}